// Round 12
// baseline (492.773 us; speedup 1.0000x reference)
//
#include <hip/hip_runtime.h>
#include <hip/hip_fp16.h>

constexpr int N_NODES = 100000;
constexpr int N_EDGES = 3200000;
constexpr int NB2 = (N_NODES + 63) >> 6;     // 1563 lists, 64 dst-nodes each
constexpr int LCAP = 2432;                   // mean 2048, sd ~45 -> +8.5 sigma
constexpr int TILE2 = 12500;                 // 3.2M / 256 exactly
constexpr int NTILE2 = N_EDGES / TILE2;      // 256 tiles
constexpr int NWIN = 8;                      // src>>14 windows (0..6 used; 4MB fp16 each)
constexpr int NKEY = NWIN * 64;              // 512 keys: WINDOW-major, row-minor

// ---------------------------------------------------------------------------
// K0: x (fp32) -> xh (fp16). ~77 MB streamed; absmax unchanged (round-8).
// ---------------------------------------------------------------------------
__global__ __launch_bounds__(256) void cvt_kernel(const float* __restrict__ x,
                                                  __half* __restrict__ xh) {
  const int stride = gridDim.x * 256;
  const int total = N_NODES * 128 / 4;
  for (int i = blockIdx.x * 256 + threadIdx.x; i < total; i += stride) {
    float4 v = ((const float4*)x)[i];
    ((__half2*)xh)[2 * i] = __floats2half2_rn(v.x, v.y);
    ((__half2*)xh)[2 * i + 1] = __floats2half2_rn(v.z, v.w);
  }
}

// ---------------------------------------------------------------------------
// bin v6: ZERO global atomics (round-11 diagnosis: the claim phase's 400K
// atomic RMWs on 1563 counters = ~98 cache lines hammered by 256 concurrent
// blocks -> same-line serialization ~100+us). Radix-sort-pass structure:
//   K_hist:    per-tile LDS histogram -> cnt[l][t]   (plain stores)
//   K_scan:    per-list 256-wide scan -> bases[l][t], gtail[l]
//   K_scatter: in-LDS counting sort (bin5) with lbase LOADED, not claimed
// ---------------------------------------------------------------------------
__global__ __launch_bounds__(1024) void hist_kernel(const int* __restrict__ dst,
                                                    int* __restrict__ cnt) {
  __shared__ int lcnt[NB2];
  const int t = threadIdx.x;
  const int e0 = blockIdx.x * TILE2;
  for (int i = t; i < NB2; i += 1024) lcnt[i] = 0;
  __syncthreads();
  for (int i = t; i < TILE2; i += 1024)
    atomicAdd(&lcnt[dst[e0 + i] >> 6], 1);      // dst<100000 -> l<=1562
  __syncthreads();
  for (int i = t; i < NB2; i += 1024) cnt[i * 256 + blockIdx.x] = lcnt[i];
}

__global__ __launch_bounds__(256) void scan_kernel(const int* __restrict__ cnt,
                                                   int* __restrict__ bases,
                                                   int* __restrict__ gtail) {
  const int wv = threadIdx.x >> 6, lane = threadIdx.x & 63;
  const int l = blockIdx.x * 4 + wv;
  if (l >= NB2) return;
  int4 c4 = ((const int4*)(cnt + (size_t)l * 256))[lane];
  int sum = ((c4.x + c4.y) + (c4.z + c4.w));
  int inc = sum;
  #pragma unroll
  for (int d = 1; d < 64; d <<= 1) {
    int u = __shfl_up(inc, d, 64);
    if (lane >= d) inc += u;
  }
  int excl = inc - sum;
  int4 b4;
  b4.x = excl;
  b4.y = excl + c4.x;
  b4.z = excl + c4.x + c4.y;
  b4.w = excl + c4.x + c4.y + c4.z;
  ((int4*)(bases + (size_t)l * 256))[lane] = b4;
  if (lane == 63) gtail[l] = inc;
}

__global__ __launch_bounds__(1024) void scatter_kernel(
    const int* __restrict__ src, const int* __restrict__ dst,
    const float* __restrict__ w, const int* __restrict__ bases,
    int2* __restrict__ lists) {
  __shared__ int2 rec[TILE2];               // 100000 B
  __shared__ unsigned short lid[TILE2];     // 25000 B
  __shared__ int lcnt[NB2];
  __shared__ int loff[NB2];
  __shared__ int lbase[NB2];
  __shared__ int wsum[16];
  const int t = threadIdx.x;
  const int e0 = blockIdx.x * TILE2;

  for (int i = t; i < NB2; i += 1024) lcnt[i] = 0;
  __syncthreads();

  for (int i = t; i < TILE2; i += 1024)
    atomicAdd(&lcnt[dst[e0 + i] >> 6], 1);
  __syncthreads();

  // block-wide exclusive scan over 1563 counters (2 slots/thread)
  {
    int i0 = 2 * t, i1 = 2 * t + 1;
    int c0 = (i0 < NB2) ? lcnt[i0] : 0;
    int c1 = (i1 < NB2) ? lcnt[i1] : 0;
    int v = c0 + c1;
    int inc = v;
    #pragma unroll
    for (int d = 1; d < 64; d <<= 1) {
      int u = __shfl_up(inc, d, 64);
      if ((t & 63) >= d) inc += u;
    }
    if ((t & 63) == 63) wsum[t >> 6] = inc;
    __syncthreads();
    if (t < 16) {
      int s = wsum[t];
      int inc2 = s;
      #pragma unroll
      for (int d = 1; d < 16; d <<= 1) {
        int u = __shfl_up(inc2, d, 64);
        if (t >= d) inc2 += u;
      }
      wsum[t] = inc2 - s;
    }
    __syncthreads();
    int excl = (inc - v) + wsum[t >> 6];
    if (i0 < NB2) loff[i0] = excl;
    if (i1 < NB2) loff[i1] = excl + c0;
  }
  __syncthreads();

  // deterministic global bases (NO atomics), cursor <- loff
  for (int i = t; i < NB2; i += 1024) lbase[i] = bases[(size_t)i * 256 + blockIdx.x];
  __syncthreads();
  for (int i = t; i < NB2; i += 1024) lcnt[i] = loff[i];
  __syncthreads();

  // scatter records into LDS (sorted by list within tile)
  for (int i = t; i < TILE2; i += 1024) {
    int e = e0 + i;
    int d = dst[e];
    int l = d >> 6;
    int p = atomicAdd(&lcnt[l], 1);          // p < TILE2 by construction
    rec[p] = make_int2(src[e] | ((d & 63) << 17), __float_as_int(w[e]));
    lid[p] = (unsigned short)l;
  }
  __syncthreads();

  // coalesced copy-out: consecutive q -> consecutive dest within a segment
  for (int q = t; q < TILE2; q += 1024) {
    int l = lid[q];
    int dest = lbase[l] + (q - loff[l]);
    if ((unsigned)dest < (unsigned)LCAP)
      lists[(size_t)l * LCAP + dest] = rec[q];
  }
}

// ---------------------------------------------------------------------------
// K2 (agg v7): window-major phases (agg5's FETCH=166MB locality) WITH flat-
// range 8-deep ILP (agg4's pipeline). Key = win*64+row; per window, wave wv
// processes [koff[s*64+wv*16], koff[s*64+wv*16+16]) FLAT. Records are row-
// sorted and row is wave-uniform -> register accumulate + flush-on-row-change
// into a per-wave LDS accumulator (plain read-add-write: wave-private rows,
// lane-private columns, NO fp atomics - round-3 lesson). Permuted layout
// [row][lane]/[row][64+lane] = 2 lanes/bank = conflict-free.
// LDS 58.6 KB -> 2 blocks/CU.
// ---------------------------------------------------------------------------
__global__ __launch_bounds__(256) void agg7_kernel(
    const __half* __restrict__ xh, const int2* __restrict__ lists,
    const int* __restrict__ gtail, float* __restrict__ agg_out,
    float* __restrict__ sw) {
  __shared__ int2 sorted[LCAP];              // 19456 B
  __shared__ float acc_lds[4][16][128];      // 32768 B
  __shared__ float swl[64];
  __shared__ int kcnt[NKEY];
  __shared__ int koff[NKEY + 1];
  __shared__ int kcur[NKEY];
  const int b = blockIdx.x;
  const int t = threadIdx.x;
  const int c = min(gtail[b], LCAP);
  const int2* base = lists + (size_t)b * LCAP;

  for (int i = t; i < NKEY; i += 256) kcnt[i] = 0;
  for (int i = t; i < 4 * 16 * 128; i += 256) ((float*)acc_lds)[i] = 0.f;
  if (t < 64) swl[t] = 0.f;
  __syncthreads();

  // phase 1: histogram keys (win*64+row; masked -> key<512)
  for (int j = t; j < c; j += 256) {
    int rx = base[j].x;
    int key = ((rx & 0x1FFFF) >> 14) * 64 + ((rx >> 17) & 63);
    atomicAdd(&kcnt[key], 1);
  }
  __syncthreads();

  // wave-0 scan of 512 keys: 8 keys/lane local prefix + shfl scan
  if (t < 64) {
    int base8 = t * 8;
    int loc[8], run = 0;
    #pragma unroll
    for (int i = 0; i < 8; ++i) { loc[i] = run; run += kcnt[base8 + i]; }
    int inc = run;
    #pragma unroll
    for (int d = 1; d < 64; d <<= 1) {
      int u = __shfl_up(inc, d, 64);
      if (t >= d) inc += u;
    }
    int excl = inc - run;
    #pragma unroll
    for (int i = 0; i < 8; ++i) {
      koff[base8 + i] = excl + loc[i];
      kcur[base8 + i] = excl + loc[i];
    }
    if (t == 63) koff[NKEY] = inc;
  }
  __syncthreads();

  // phase 2: counting-sort scatter into LDS (guarded)
  for (int j = t; j < c; j += 256) {
    int2 r = base[j];
    int key = ((r.x & 0x1FFFF) >> 14) * 64 + ((r.x >> 17) & 63);
    int p = atomicAdd(&kcur[key], 1);
    if ((unsigned)p < (unsigned)LCAP) sorted[p] = r;
  }
  __syncthreads();

  // phase 3: per-window flat sweep, flush-on-row-change
  const int wv = t >> 6, lane = t & 63;
  const int nd = min(64, N_NODES - b * 64);
  const __half2* xh2 = (const __half2*)xh;
  float2 racc = make_float2(0.f, 0.f);
  float rsws = 0.f;
  int cur = -1;

#define FLUSH()                                              \
  if (cur >= 0) {                                            \
    int rl_ = cur & 15;                                      \
    acc_lds[wv][rl_][lane] += racc.x;                        \
    acc_lds[wv][rl_][64 + lane] += racc.y;                   \
    if (lane == 0) swl[(wv << 4) + rl_] += rsws;             \
    racc.x = 0.f; racc.y = 0.f; rsws = 0.f;                  \
  }

  for (int s = 0; s < NWIN; ++s) {
    int j0 = min(koff[s * 64 + (wv << 4)], c);
    int j1 = min(koff[s * 64 + (wv << 4) + 16], c);
    int j = j0;
    for (; j + 8 <= j1; j += 8) {
      int2 e[8];
      float2 v[8];
      #pragma unroll
      for (int i = 0; i < 8; ++i) e[i] = sorted[j + i];
      #pragma unroll
      for (int i = 0; i < 8; ++i)
        v[i] = __half22float2(xh2[(size_t)(e[i].x & 0x1FFFF) * 64 + lane]);
      #pragma unroll
      for (int i = 0; i < 8; ++i) {
        int row = (e[i].x >> 17) & 63;                 // wave-uniform
        if (row != cur) { FLUSH(); cur = row; }
        float wt = __int_as_float(e[i].y);
        racc.x = fmaf(wt, v[i].x, racc.x);
        racc.y = fmaf(wt, v[i].y, racc.y);
        rsws += wt;
      }
    }
    for (; j < j1; ++j) {
      int2 e0 = sorted[j];
      float2 v0 = __half22float2(xh2[(size_t)(e0.x & 0x1FFFF) * 64 + lane]);
      int row = (e0.x >> 17) & 63;
      if (row != cur) { FLUSH(); cur = row; }
      float wt = __int_as_float(e0.y);
      racc.x = fmaf(wt, v0.x, racc.x);
      racc.y = fmaf(wt, v0.y, racc.y);
      rsws += wt;
    }
  }
  FLUSH();
#undef FLUSH

  // write out own rows (wave-private -> no barrier needed)
  for (int ri = 0; ri < 16; ++ri) {
    int r = (wv << 4) + ri;
    if (r < nd) {
      float2 o = make_float2(acc_lds[wv][ri][lane], acc_lds[wv][ri][64 + lane]);
      ((float2*)agg_out)[(size_t)(b * 64 + r) * 64 + lane] = o;
      if (lane == 0) sw[b * 64 + r] = swl[r];
    }
  }
}

// ---------------------------------------------------------------------------
// K3 (linear v3, unchanged): in-place io[r] = io[r]@W^T + sw[r]*b, 64-row
// tiles, Wt-only LDS (2 blocks/CU), broadcast row loads. In-place safe:
// each row read AND written only by the same 16 lanes of one wave.
// ---------------------------------------------------------------------------
__global__ __launch_bounds__(256, 2) void linear3_kernel(
    float* __restrict__ io, const float* __restrict__ W,
    const float* __restrict__ bias, const float* __restrict__ sw) {
  __shared__ float Wt[128][132];   // Wt[k][c] = W[c][k]
  const int t = threadIdx.x;
  const int row0 = blockIdx.x * 64;

  #pragma unroll
  for (int i = 0; i < 16; ++i) {
    int f4 = t + 256 * i;
    int c = f4 >> 5;
    int k = (f4 & 31) * 4;
    float4 v = *(const float4*)(W + (size_t)c * 128 + k);
    Wt[k + 0][c] = v.x;
    Wt[k + 1][c] = v.y;
    Wt[k + 2][c] = v.z;
    Wt[k + 3][c] = v.w;
  }
  __syncthreads();

  const int tx = t & 15;
  const int ty = t >> 4;
  const float* xr[4];
  #pragma unroll
  for (int i = 0; i < 4; ++i) {
    int r = row0 + ty * 4 + i;
    xr[i] = (r < N_NODES) ? (io + (size_t)r * 128) : io;
  }

  float acc[4][8];
  #pragma unroll
  for (int i = 0; i < 4; ++i)
    #pragma unroll
    for (int j = 0; j < 8; ++j) acc[i][j] = 0.f;

  for (int k0 = 0; k0 < 128; k0 += 4) {
    float4 a[4];
    #pragma unroll
    for (int i = 0; i < 4; ++i) a[i] = *(const float4*)(xr[i] + k0);
    #pragma unroll
    for (int kk = 0; kk < 4; ++kk) {
      int k = k0 + kk;
      float4 b0 = *(const float4*)&Wt[k][tx * 8];
      float4 b1 = *(const float4*)&Wt[k][tx * 8 + 4];
      #pragma unroll
      for (int i = 0; i < 4; ++i) {
        float av = (kk == 0) ? a[i].x : (kk == 1) ? a[i].y
                  : (kk == 2) ? a[i].z : a[i].w;
        acc[i][0] = fmaf(av, b0.x, acc[i][0]);
        acc[i][1] = fmaf(av, b0.y, acc[i][1]);
        acc[i][2] = fmaf(av, b0.z, acc[i][2]);
        acc[i][3] = fmaf(av, b0.w, acc[i][3]);
        acc[i][4] = fmaf(av, b1.x, acc[i][4]);
        acc[i][5] = fmaf(av, b1.y, acc[i][5]);
        acc[i][6] = fmaf(av, b1.z, acc[i][6]);
        acc[i][7] = fmaf(av, b1.w, acc[i][7]);
      }
    }
  }

  float4 bb0 = *(const float4*)(bias + tx * 8);
  float4 bb1 = *(const float4*)(bias + tx * 8 + 4);
  #pragma unroll
  for (int i = 0; i < 4; ++i) {
    int r = row0 + ty * 4 + i;
    if (r < N_NODES) {
      float s = sw[r];
      float4 o0 = make_float4(acc[i][0] + s * bb0.x, acc[i][1] + s * bb0.y,
                              acc[i][2] + s * bb0.z, acc[i][3] + s * bb0.w);
      float4 o1 = make_float4(acc[i][4] + s * bb1.x, acc[i][5] + s * bb1.y,
                              acc[i][6] + s * bb1.z, acc[i][7] + s * bb1.w);
      float* orow = io + (size_t)r * 128 + tx * 8;
      *(float4*)orow = o0;
      *(float4*)(orow + 4) = o1;
    }
  }
}

// ---------------------------------------------------------------------------
extern "C" void kernel_launch(void* const* d_in, const int* in_sizes, int n_in,
                              void* d_out, int out_size, void* d_ws, size_t ws_size,
                              hipStream_t stream) {
  const float* x = (const float*)d_in[0];
  const float* w = (const float*)d_in[1];
  const float* W = (const float*)d_in[2];
  const float* bias = (const float*)d_in[3];
  const int* src = (const int*)d_in[4];
  const int* dst = (const int*)d_in[5];
  float* out = (float*)d_out;

  // ws: xh 25.6MB | lists 30.4MB | cnt 1.6MB | bases 1.6MB | gtail | sw (~60MB)
  char* p = (char*)d_ws;
  __half* xh = (__half*)p;
  size_t o = (size_t)N_NODES * 128 * sizeof(__half);
  o = (o + 255) & ~(size_t)255;
  int2* lists = (int2*)(p + o);
  o += (size_t)NB2 * LCAP * sizeof(int2);
  o = (o + 255) & ~(size_t)255;
  int* cnt = (int*)(p + o);
  o += (size_t)NB2 * 256 * sizeof(int);
  o = (o + 255) & ~(size_t)255;
  int* bases = (int*)(p + o);
  o += (size_t)NB2 * 256 * sizeof(int);
  o = (o + 255) & ~(size_t)255;
  int* gtail = (int*)(p + o);
  o += (size_t)NB2 * sizeof(int);
  o = (o + 255) & ~(size_t)255;
  float* sw = (float*)(p + o);

  cvt_kernel<<<2048, 256, 0, stream>>>(x, xh);
  hist_kernel<<<NTILE2, 1024, 0, stream>>>(dst, cnt);
  scan_kernel<<<(NB2 + 3) / 4, 256, 0, stream>>>(cnt, bases, gtail);
  scatter_kernel<<<NTILE2, 1024, 0, stream>>>(src, dst, w, bases, lists);
  agg7_kernel<<<NB2, 256, 0, stream>>>(xh, lists, gtail, out, sw);
  linear3_kernel<<<NB2, 256, 0, stream>>>(out, W, bias, sw);
}

// Round 13
// 427.287 us; speedup vs baseline: 1.1533x; 1.1533x over previous
//
#include <hip/hip_runtime.h>
#include <hip/hip_fp16.h>

constexpr int N_NODES = 100000;
constexpr int N_EDGES = 3200000;
constexpr int NB2 = (N_NODES + 63) >> 6;     // 1563 buckets, 64 dst-nodes each
constexpr int LCAP = 2432;                   // bucket cap: mean 2048, sd ~45 -> +8.5 sigma
constexpr int TILE2 = 12500;                 // 3.2M / 256 exactly
constexpr int NTILE2 = N_EDGES / TILE2;      // 256 tiles
constexpr int LSTRIDE = NB2 + 1;             // 1564

// ---------------------------------------------------------------------------
// K0: x (fp32) -> xh (fp16). ~77 MB streamed; absmax unchanged (round-8).
// ---------------------------------------------------------------------------
__global__ __launch_bounds__(256) void cvt_kernel(const float* __restrict__ x,
                                                  __half* __restrict__ xh) {
  const int stride = gridDim.x * 256;
  const int total = N_NODES * 128 / 4;
  for (int i = blockIdx.x * 256 + threadIdx.x; i < total; i += stride) {
    float4 v = ((const float4*)x)[i];
    ((__half2*)xh)[2 * i] = __floats2half2_rn(v.x, v.y);
    ((__half2*)xh)[2 * i + 1] = __floats2half2_rn(v.z, v.w);
  }
}

// ---------------------------------------------------------------------------
// K1 (bin_t): in-LDS counting sort by bucket id within each 12500-edge tile,
// output TILE-MAJOR: recs[e0+q] (perfectly coalesced 100KB/block) + offset
// row loffm[tile][l]. Deletes ALL list-major scattered global writes, claim
// atomics, gtail/scan/bases kernels, memsets (R12 falsified the atomic-
// contention theory; R11/R12 write paths both ~150us -> this isolates the
// LDS-sort cost). Record = int2{ src | (dst&63)<<17 , w_bits }.
// LDS: rec 100000 + lcnt 6252 + loff 6256 + wsum = ~110 KB, 1 block/CU.
// ---------------------------------------------------------------------------
__global__ __launch_bounds__(1024) void bint_kernel(
    const int* __restrict__ src, const int* __restrict__ dst,
    const float* __restrict__ w, int2* __restrict__ recs,
    int* __restrict__ loffm) {
  __shared__ int2 rec[TILE2];               // 100000 B
  __shared__ int lcnt[NB2];                 // counts, then cursor
  __shared__ int loff[NB2];                 // tile-local exclusive offsets
  __shared__ int wsum[16];
  const int t = threadIdx.x;
  const int e0 = blockIdx.x * TILE2;

  for (int i = t; i < NB2; i += 1024) lcnt[i] = 0;
  __syncthreads();

  // pass A: histogram of bucket id (native int ds_add)
  for (int i = t; i < TILE2; i += 1024)
    atomicAdd(&lcnt[dst[e0 + i] >> 6], 1);   // dst<100000 -> l<=1562
  __syncthreads();

  // block-wide exclusive scan over 1563 counters (2 slots/thread)
  {
    int i0 = 2 * t, i1 = 2 * t + 1;
    int c0 = (i0 < NB2) ? lcnt[i0] : 0;
    int c1 = (i1 < NB2) ? lcnt[i1] : 0;
    int v = c0 + c1;
    int inc = v;
    #pragma unroll
    for (int d = 1; d < 64; d <<= 1) {
      int u = __shfl_up(inc, d, 64);
      if ((t & 63) >= d) inc += u;
    }
    if ((t & 63) == 63) wsum[t >> 6] = inc;
    __syncthreads();
    if (t < 16) {
      int s = wsum[t];
      int inc2 = s;
      #pragma unroll
      for (int d = 1; d < 16; d <<= 1) {
        int u = __shfl_up(inc2, d, 64);
        if (t >= d) inc2 += u;
      }
      wsum[t] = inc2 - s;
    }
    __syncthreads();
    int excl = (inc - v) + wsum[t >> 6];
    if (i0 < NB2) loff[i0] = excl;
    if (i1 < NB2) loff[i1] = excl + c0;
  }
  __syncthreads();

  // cursor <- loff
  for (int i = t; i < NB2; i += 1024) lcnt[i] = loff[i];
  __syncthreads();

  // pass B: re-read tile (L2-hot), scatter records into LDS sorted-by-bucket
  for (int i = t; i < TILE2; i += 1024) {
    int e = e0 + i;
    int d = dst[e];
    int l = d >> 6;
    int p = atomicAdd(&lcnt[l], 1);          // p < TILE2 by construction
    rec[p] = make_int2(src[e] | ((d & 63) << 17), __float_as_int(w[e]));
  }
  __syncthreads();

  // copy-out: PERFECTLY coalesced (identity within tile)
  for (int q = t; q < TILE2; q += 1024) recs[(size_t)e0 + q] = rec[q];
  // offset row for this tile
  for (int i = t; i < NB2; i += 1024)
    loffm[(size_t)blockIdx.x * LSTRIDE + i] = loff[i];
  if (t == 0) loffm[(size_t)blockIdx.x * LSTRIDE + NB2] = TILE2;
}

// ---------------------------------------------------------------------------
// K2 (agg v8): agg4 structure (the measured-best gather: 64-key row sort,
// 16 rows/wave, 8-deep flat ILP, 20KB LDS -> agg4's occupancy) with the
// contiguous list reads replaced by per-tile segment walks. Thread t<256
// owns tile t's segment [loffm[t][b], loffm[t][b+1]) : walk twice (row
// histogram, then scatter into sorted[] via int cursor - NO fp atomics,
// round-3 lesson). Phase 3 verbatim agg4.
// ---------------------------------------------------------------------------
__global__ __launch_bounds__(256) void agg8_kernel(
    const __half* __restrict__ xh, const int2* __restrict__ recs,
    const int* __restrict__ loffm, float* __restrict__ agg_out,
    float* __restrict__ sw) {
  __shared__ int2 sorted[LCAP];          // 19456 B
  __shared__ int rcnt[64], roff[65], rcur[64];
  const int b = blockIdx.x;
  const int t = threadIdx.x;

  // this thread's tile segment for bucket b
  const int j0 = loffm[(size_t)t * LSTRIDE + b];
  const int j1 = loffm[(size_t)t * LSTRIDE + b + 1];
  const int2* seg = recs + (size_t)t * TILE2;

  if (t < 64) rcnt[t] = 0;
  __syncthreads();

  // phase 1: row histogram (walk segment; masked index -> [0,64))
  for (int j = j0; j < j1; ++j)
    atomicAdd(&rcnt[(seg[j].x >> 17) & 63], 1);
  __syncthreads();

  // wave-0 shfl scan of 64 counters
  if (t < 64) {
    int v = rcnt[t];
    int inc = v;
    #pragma unroll
    for (int d = 1; d < 64; d <<= 1) {
      int u = __shfl_up(inc, d, 64);
      if (t >= d) inc += u;
    }
    roff[t] = inc - v;
    rcur[t] = inc - v;
    if (t == 63) roff[64] = inc;
  }
  __syncthreads();

  // phase 2: scatter into LDS sorted-by-row (walk again; L2-hot; guarded)
  for (int j = j0; j < j1; ++j) {
    int2 r = seg[j];
    int p = atomicAdd(&rcur[(r.x >> 17) & 63], 1);
    if ((unsigned)p < (unsigned)LCAP) sorted[p] = r;
  }
  __syncthreads();

  // phase 3 (verbatim agg4): 16 rows/wave, 8 fp16 gathers in flight
  const int wv = t >> 6, lane = t & 63;
  const int nd = min(64, N_NODES - b * 64);
  const __half2* xh2 = (const __half2*)xh;
  for (int ri = 0; ri < 16; ++ri) {
    int r = wv * 16 + ri;
    int s0 = min(roff[r], LCAP), s1 = min(roff[r + 1], LCAP);
    float2 acc = make_float2(0.f, 0.f);
    float sws = 0.f;
    int j = s0;
    for (; j + 8 <= s1; j += 8) {
      int2 e0 = sorted[j];
      int2 e1 = sorted[j + 1];
      int2 e2 = sorted[j + 2];
      int2 e3 = sorted[j + 3];
      int2 e4 = sorted[j + 4];
      int2 e5 = sorted[j + 5];
      int2 e6 = sorted[j + 6];
      int2 e7 = sorted[j + 7];
      __half2 h0 = xh2[(size_t)(e0.x & 0x1FFFF) * 64 + lane];
      __half2 h1 = xh2[(size_t)(e1.x & 0x1FFFF) * 64 + lane];
      __half2 h2 = xh2[(size_t)(e2.x & 0x1FFFF) * 64 + lane];
      __half2 h3 = xh2[(size_t)(e3.x & 0x1FFFF) * 64 + lane];
      __half2 h4 = xh2[(size_t)(e4.x & 0x1FFFF) * 64 + lane];
      __half2 h5 = xh2[(size_t)(e5.x & 0x1FFFF) * 64 + lane];
      __half2 h6 = xh2[(size_t)(e6.x & 0x1FFFF) * 64 + lane];
      __half2 h7 = xh2[(size_t)(e7.x & 0x1FFFF) * 64 + lane];
      float2 v0 = __half22float2(h0);
      float2 v1 = __half22float2(h1);
      float2 v2 = __half22float2(h2);
      float2 v3 = __half22float2(h3);
      float2 v4 = __half22float2(h4);
      float2 v5 = __half22float2(h5);
      float2 v6 = __half22float2(h6);
      float2 v7 = __half22float2(h7);
      float w0 = __int_as_float(e0.y), w1 = __int_as_float(e1.y);
      float w2 = __int_as_float(e2.y), w3 = __int_as_float(e3.y);
      float w4 = __int_as_float(e4.y), w5 = __int_as_float(e5.y);
      float w6 = __int_as_float(e6.y), w7 = __int_as_float(e7.y);
      acc.x = fmaf(w0, v0.x, acc.x); acc.y = fmaf(w0, v0.y, acc.y);
      acc.x = fmaf(w1, v1.x, acc.x); acc.y = fmaf(w1, v1.y, acc.y);
      acc.x = fmaf(w2, v2.x, acc.x); acc.y = fmaf(w2, v2.y, acc.y);
      acc.x = fmaf(w3, v3.x, acc.x); acc.y = fmaf(w3, v3.y, acc.y);
      acc.x = fmaf(w4, v4.x, acc.x); acc.y = fmaf(w4, v4.y, acc.y);
      acc.x = fmaf(w5, v5.x, acc.x); acc.y = fmaf(w5, v5.y, acc.y);
      acc.x = fmaf(w6, v6.x, acc.x); acc.y = fmaf(w6, v6.y, acc.y);
      acc.x = fmaf(w7, v7.x, acc.x); acc.y = fmaf(w7, v7.y, acc.y);
      sws += ((w0 + w1) + (w2 + w3)) + ((w4 + w5) + (w6 + w7));
    }
    for (; j < s1; ++j) {
      int2 e0 = sorted[j];
      float2 v0 = __half22float2(xh2[(size_t)(e0.x & 0x1FFFF) * 64 + lane]);
      float w0 = __int_as_float(e0.y);
      acc.x = fmaf(w0, v0.x, acc.x);
      acc.y = fmaf(w0, v0.y, acc.y);
      sws += w0;
    }
    if (r < nd) {
      ((float2*)agg_out)[(size_t)(b * 64 + r) * 64 + lane] = acc;
      if (lane == 0) sw[b * 64 + r] = sws;
    }
  }
}

// ---------------------------------------------------------------------------
// K3 (linear v3, unchanged): in-place io[r] = io[r]@W^T + sw[r]*b, 64-row
// tiles, Wt-only LDS (2 blocks/CU), broadcast row loads. In-place safe:
// each row read AND written only by the same 16 lanes of one wave.
// ---------------------------------------------------------------------------
__global__ __launch_bounds__(256, 2) void linear3_kernel(
    float* __restrict__ io, const float* __restrict__ W,
    const float* __restrict__ bias, const float* __restrict__ sw) {
  __shared__ float Wt[128][132];   // Wt[k][c] = W[c][k]
  const int t = threadIdx.x;
  const int row0 = blockIdx.x * 64;

  #pragma unroll
  for (int i = 0; i < 16; ++i) {
    int f4 = t + 256 * i;
    int c = f4 >> 5;
    int k = (f4 & 31) * 4;
    float4 v = *(const float4*)(W + (size_t)c * 128 + k);
    Wt[k + 0][c] = v.x;
    Wt[k + 1][c] = v.y;
    Wt[k + 2][c] = v.z;
    Wt[k + 3][c] = v.w;
  }
  __syncthreads();

  const int tx = t & 15;
  const int ty = t >> 4;
  const float* xr[4];
  #pragma unroll
  for (int i = 0; i < 4; ++i) {
    int r = row0 + ty * 4 + i;
    xr[i] = (r < N_NODES) ? (io + (size_t)r * 128) : io;
  }

  float acc[4][8];
  #pragma unroll
  for (int i = 0; i < 4; ++i)
    #pragma unroll
    for (int j = 0; j < 8; ++j) acc[i][j] = 0.f;

  for (int k0 = 0; k0 < 128; k0 += 4) {
    float4 a[4];
    #pragma unroll
    for (int i = 0; i < 4; ++i) a[i] = *(const float4*)(xr[i] + k0);
    #pragma unroll
    for (int kk = 0; kk < 4; ++kk) {
      int k = k0 + kk;
      float4 b0 = *(const float4*)&Wt[k][tx * 8];
      float4 b1 = *(const float4*)&Wt[k][tx * 8 + 4];
      #pragma unroll
      for (int i = 0; i < 4; ++i) {
        float av = (kk == 0) ? a[i].x : (kk == 1) ? a[i].y
                  : (kk == 2) ? a[i].z : a[i].w;
        acc[i][0] = fmaf(av, b0.x, acc[i][0]);
        acc[i][1] = fmaf(av, b0.y, acc[i][1]);
        acc[i][2] = fmaf(av, b0.z, acc[i][2]);
        acc[i][3] = fmaf(av, b0.w, acc[i][3]);
        acc[i][4] = fmaf(av, b1.x, acc[i][4]);
        acc[i][5] = fmaf(av, b1.y, acc[i][5]);
        acc[i][6] = fmaf(av, b1.z, acc[i][6]);
        acc[i][7] = fmaf(av, b1.w, acc[i][7]);
      }
    }
  }

  float4 bb0 = *(const float4*)(bias + tx * 8);
  float4 bb1 = *(const float4*)(bias + tx * 8 + 4);
  #pragma unroll
  for (int i = 0; i < 4; ++i) {
    int r = row0 + ty * 4 + i;
    if (r < N_NODES) {
      float s = sw[r];
      float4 o0 = make_float4(acc[i][0] + s * bb0.x, acc[i][1] + s * bb0.y,
                              acc[i][2] + s * bb0.z, acc[i][3] + s * bb0.w);
      float4 o1 = make_float4(acc[i][4] + s * bb1.x, acc[i][5] + s * bb1.y,
                              acc[i][6] + s * bb1.z, acc[i][7] + s * bb1.w);
      float* orow = io + (size_t)r * 128 + tx * 8;
      *(float4*)orow = o0;
      *(float4*)(orow + 4) = o1;
    }
  }
}

// ---------------------------------------------------------------------------
extern "C" void kernel_launch(void* const* d_in, const int* in_sizes, int n_in,
                              void* d_out, int out_size, void* d_ws, size_t ws_size,
                              hipStream_t stream) {
  const float* x = (const float*)d_in[0];
  const float* w = (const float*)d_in[1];
  const float* W = (const float*)d_in[2];
  const float* bias = (const float*)d_in[3];
  const int* src = (const int*)d_in[4];
  const int* dst = (const int*)d_in[5];
  float* out = (float*)d_out;

  // ws: xh 25.6MB | recs 25.6MB | loffm 1.6MB | sw 400KB  (~53.2MB)
  char* p = (char*)d_ws;
  __half* xh = (__half*)p;
  size_t o = (size_t)N_NODES * 128 * sizeof(__half);
  o = (o + 255) & ~(size_t)255;
  int2* recs = (int2*)(p + o);
  o += (size_t)N_EDGES * sizeof(int2);
  o = (o + 255) & ~(size_t)255;
  int* loffm = (int*)(p + o);
  o += (size_t)NTILE2 * LSTRIDE * sizeof(int);
  o = (o + 255) & ~(size_t)255;
  float* sw = (float*)(p + o);

  cvt_kernel<<<2048, 256, 0, stream>>>(x, xh);
  bint_kernel<<<NTILE2, 1024, 0, stream>>>(src, dst, w, recs, loffm);
  agg8_kernel<<<NB2, 256, 0, stream>>>(xh, recs, loffm, out, sw);
  linear3_kernel<<<NB2, 256, 0, stream>>>(out, W, bias, sw);
}